// Round 7
// baseline (159.520 us; speedup 1.0000x reference)
//
#include <hip/hip_runtime.h>
#include <hip/hip_bf16.h>
#include <stdint.h>

typedef __hip_bfloat16 bf16;
typedef __attribute__((ext_vector_type(8))) short short8;   // 8 bf16 = 4 VGPRs (MFMA A/B frag)
typedef __attribute__((ext_vector_type(4))) float floatx4;  // MFMA C/D frag
typedef __attribute__((ext_vector_type(4))) short s4v;      // 8B bf16 vector store

#define MFMA_BF16(a, b, c) __builtin_amdgcn_mfma_f32_16x16x32_bf16((a), (b), (c), 0, 0, 0)

// Problem constants: B=2, N=2048, C=1024, H=8, D=128, half-window 128.
// qkv workspace layout: [b][n][3*C] with col = which*1024 + h*128 + d
//   (V columns are NOT written to qkv — V lives only in Vt)
// Vt layout: [b][h][d][n]  (PV B-frags contiguous in key)
//
// Session laws:
//  R3/R4: waves/CU & refetch dominate the 2-barrier template.
//  R5: coarse counted-vmcnt (tri-buffer) NULL.
//  R6: full 8-phase port = 55.8us @ MfmaUtil 17% — at K=1024 (16 tiles) the
//      deep pipeline never fills; 2 waves/SIMD park at barriers. GEMM1 is at
//      its structural plateau (~52.6us across 3 structures) — stop.
//  R7 (this round): GEMM1 reverted to R2 config. GEMM2 moves from 1 lockstep
//      block/CU (8w x 1 domain) to 4 blocks/CU (4w x 4 domains, same 128^2
//      tile -> refetch unchanged), occupancy law applied.

// ---------------------------------------------------------------------------
// async global->LDS 16B copy: LDS dst is wave-uniform (lane i lands at
// dst + i*16 bytes); gsrc is per-lane (arbitrary gather). [m97/m104-verified]
// ---------------------------------------------------------------------------
__device__ __forceinline__ void gl_lds16(const bf16* gsrc, bf16* lds_dst)
{
    __builtin_amdgcn_global_load_lds(
        (const __attribute__((address_space(1))) uint32_t*)(uintptr_t)gsrc,
        (__attribute__((address_space(3))) uint32_t*)(uintptr_t)lds_dst,
        16, 0, 0);
}

// ---------------------------------------------------------------------------
// Dtype sniff: bf16 N(0,1) halfword[2i] has exponent in [100,140] ~always;
// fp32 low-mantissa halfwords hit that band ~16%.
// ---------------------------------------------------------------------------
__device__ __forceinline__ int sniff_bf16(const uint16_t* __restrict__ x)
{
    int cnt = 0;
#pragma unroll
    for (int i = 0; i < 64; ++i) {
        const int e = (x[2 * i] >> 7) & 0xFF;
        cnt += (e >= 100 && e <= 140) ? 1 : 0;
    }
    return (cnt >= 32) ? 1 : 0;
}

// ---------------------------------------------------------------------------
// One fused conversion kernel: x / w_qkv / w_proj -> bf16 (8 elems/thread),
// biases -> fp32. Grid = 4100 blocks x 256.
// ---------------------------------------------------------------------------
__global__ void __launch_bounds__(256)
cvt_all_kernel(const void* __restrict__ x, const void* __restrict__ wq,
               const void* __restrict__ wp, const void* __restrict__ bq,
               const void* __restrict__ bp,
               bf16* __restrict__ xb, bf16* __restrict__ wqb,
               bf16* __restrict__ wpb, float* __restrict__ bqf,
               float* __restrict__ bpf)
{
    __shared__ int sflag;
    if (threadIdx.x == 0) sflag = sniff_bf16((const uint16_t*)x);
    __syncthreads();
    const bool isbf = (sflag != 0);

    const int blk = blockIdx.x;
    if (blk < 4096) {
        const void* src; bf16* dst; int base;
        if (blk < 2048)      { src = x;  dst = xb;  base = blk << 11; }
        else if (blk < 3584) { src = wq; dst = wqb; base = (blk - 2048) << 11; }
        else                 { src = wp; dst = wpb; base = (blk - 3584) << 11; }
        const int i = base + (int)threadIdx.x * 8;
        if (isbf) {
            *(uint4*)(dst + i) = *(const uint4*)((const bf16*)src + i);
        } else {
            const float4 f0 = *(const float4*)((const float*)src + i);
            const float4 f1 = *(const float4*)((const float*)src + i + 4);
            bf16 o[8];
            o[0] = __float2bfloat16(f0.x); o[1] = __float2bfloat16(f0.y);
            o[2] = __float2bfloat16(f0.z); o[3] = __float2bfloat16(f0.w);
            o[4] = __float2bfloat16(f1.x); o[5] = __float2bfloat16(f1.y);
            o[6] = __float2bfloat16(f1.z); o[7] = __float2bfloat16(f1.w);
            *(uint4*)(dst + i) = *(uint4*)o;
        }
    } else {
        const void* src; float* dst; int base, n;
        if (blk < 4099) { src = bq; dst = bqf; base = (blk - 4096) * 1024; n = 3072; }
        else            { src = bp; dst = bpf; base = 0;                   n = 1024; }
        const int i0 = base + (int)threadIdx.x * 4;
#pragma unroll
        for (int k = 0; k < 4; ++k) {
            const int idx = i0 + k;
            if (idx < n)
                dst[idx] = isbf ? __bfloat162float(((const bf16*)src)[idx])
                                : ((const float*)src)[idx];
        }
    }
}

// ---------------------------------------------------------------------------
// GEMM: C[m,n] = sum_k A[m,k] * W[n,k] + bias[n]   (x @ W^T + b, W row-major)
// Parameterized 2-barrier dbuf template. BK=32. Waves form a WROWS x WCOLS
// grid; wave tile = (BM/WROWS) x (BN/WCOLS); acc = (WTM/16) x (WTN/16).
//
// Configs (R7):
//   GEMM1: 128x128, 8 waves (2x4), wave 64x32, grid (32,24)=768
//          = 3 blocks/CU = 24 waves/CU.  [R2-proven; plateau ~52.6us]
//   GEMM2: 128x128, 4 waves (2x2), wave 64x64 (acc 4x4: 16 MFMA : 8 reads),
//          grid (32,8)=256 with 4 blocks/CU (launch_bounds(256,4), 32KB LDS)
//          = 16 waves/CU in 4 INDEPENDENT barrier domains (was: 8 waves in
//          1 lockstep domain). Tile unchanged -> refetch unchanged (R3 law).
// FUSE_VT epilogue: V cols (>=2048) go ONLY to Vt (8B vector stores);
// 2048 is a multiple of 16 so the branch is uniform per 16-col frag.
// ---------------------------------------------------------------------------
template <int BM, int BN, int WROWS, int WCOLS, int MINW, bool FUSE_VT, bool DYN_OUT>
__global__ void __launch_bounds__(WROWS* WCOLS * 64, MINW)
gemm_bt_kernel(const bf16* __restrict__ A, const bf16* __restrict__ W,
               const float* __restrict__ bias, void* __restrict__ Cout,
               int M, int Nc, int K, bf16* __restrict__ Vt,
               const uint16_t* __restrict__ sniffsrc)
{
    constexpr int WAVES  = WROWS * WCOLS;
    constexpr int WTM    = BM / WROWS;
    constexpr int WTN    = BN / WCOLS;
    constexpr int AI     = WTM / 16;
    constexpr int AJ     = WTN / 16;
    constexpr int ASHOTS = BM / 16;          // 1 KB staging shots (16 rows)
    constexpr int TSHOTS = (BM + BN) / 16;

    __shared__ __align__(16) bf16 As[2][BM][32];
    __shared__ __align__(16) bf16 Bs[2][BN][32];
    __shared__ int sflag;

    const int tid  = threadIdx.x;
    const int lane = tid & 63;
    const int wave = tid >> 6;
    const int quad = lane >> 4;
    const int l16  = lane & 15;
    const int wm   = (wave % WROWS) * WTM;
    const int wn   = (wave / WROWS) * WTN;
    const int bm   = blockIdx.x * BM;
    const int bn   = blockIdx.y * BN;

    if (DYN_OUT && tid == 0) sflag = sniff_bf16(sniffsrc);

    // staging: shot s = 16 rows x 32 cols (1 KB); lane -> row lane>>2,
    // 16B col chunk lane&3. Shots round-robin over waves.
    const int srow = lane >> 2;
    const int scol = (lane & 3) * 8;
    const bf16* Abase = A + (size_t)(bm + srow) * K + scol;
    const bf16* Wbase = W + (size_t)(bn + srow) * K + scol;

    floatx4 acc[AI][AJ];
#pragma unroll
    for (int i = 0; i < AI; ++i)
#pragma unroll
        for (int j = 0; j < AJ; ++j)
#pragma unroll
            for (int r = 0; r < 4; ++r) acc[i][j][r] = 0.0f;

    auto stage = [&](int k0, int buf) {
#pragma unroll
        for (int s = wave; s < TSHOTS; s += WAVES) {
            if (s < ASHOTS) {
                gl_lds16(Abase + (size_t)(s * 16) * K + k0,
                         &As[buf][0][0] + s * 512);
            } else {
                const int t = s - ASHOTS;
                gl_lds16(Wbase + (size_t)(t * 16) * K + k0,
                         &Bs[buf][0][0] + t * 512);
            }
        }
    };

    stage(0, 0);
    const int niter = K >> 5;
    for (int it = 0; it < niter; ++it) {
        const int buf = it & 1;
        __syncthreads();                       // stage(it) complete; prev reads done
        if (it + 1 < niter) stage((it + 1) << 5, buf ^ 1);

        short8 af[AI], bfr[AJ];
#pragma unroll
        for (int i = 0; i < AI; ++i)
            af[i] = *(const short8*)(&As[buf][wm + i * 16 + l16][quad * 8]);
#pragma unroll
        for (int j = 0; j < AJ; ++j)
            bfr[j] = *(const short8*)(&Bs[buf][wn + j * 16 + l16][quad * 8]);
#pragma unroll
        for (int i = 0; i < AI; ++i)
#pragma unroll
            for (int j = 0; j < AJ; ++j)
                acc[i][j] = MFMA_BF16(af[i], bfr[j], acc[i][j]);
    }

    const bool outbf = DYN_OUT ? (sflag != 0) : true;

    // epilogue: C/D layout row = quad*4+r, col = l16
#pragma unroll
    for (int i = 0; i < AI; ++i) {
#pragma unroll
        for (int j = 0; j < AJ; ++j) {
            const int col = bn + wn + j * 16 + l16;
            const float bv = bias[col];
            if (FUSE_VT && col >= 2048) {
                // V columns: transposed store to Vt only (8B vector store;
                // rows quad*4 + r are consecutive nn in Vt's last dim)
                const int hh   = (col - 2048) >> 7;
                const int dd   = (col - 2048) & 127;
                const int row0 = bm + wm + i * 16 + quad * 4;
                const int bb   = row0 >> 11;     // M = 4096 = B*N
                const int nn   = row0 & 2047;
                __align__(8) bf16 vv[4];
#pragma unroll
                for (int r = 0; r < 4; ++r)
                    vv[r] = __float2bfloat16(acc[i][j][r] + bv);
                *(s4v*)(Vt + (((size_t)bb * 8 + hh) * 128 + dd) * 2048 + nn) =
                    *(const s4v*)vv;
            } else {
#pragma unroll
                for (int r = 0; r < 4; ++r) {
                    const int row = bm + wm + i * 16 + quad * 4 + r;
                    const float v = acc[i][j][r] + bv;
                    const size_t idx = (size_t)row * Nc + col;
                    if (!DYN_OUT || outbf) {
                        ((bf16*)Cout)[idx] = __float2bfloat16(v);
                    } else {
                        ((float*)Cout)[idx] = v;
                    }
                }
            }
        }
    }
}

// ---------------------------------------------------------------------------
// Banded attention v6 (unchanged — R2-verified): 4 waves / 64 queries;
// K/V staged in MFMA B-frag order, dbuf single-barrier pipeline; wave-private
// Plds; shift-free softmax; XCD swizzle; per-wave band chunk-skip.
// Grid 512 -> 2 blocks/CU -> 8 waves/CU.
// ---------------------------------------------------------------------------
__global__ void __launch_bounds__(256, 2)
attn_kernel(const bf16* __restrict__ qkv, const bf16* __restrict__ Vt,
            bf16* __restrict__ out)
{
    __shared__ __align__(16) bf16 Kl[2][16 * 512];   // 32 KB, frag-ordered
    __shared__ __align__(16) bf16 Vl[2][16 * 512];   // 32 KB, frag-ordered
    __shared__ __align__(16) bf16 Plds[4][16][72];   // 9.2 KB, wave-private P

    const int tid  = threadIdx.x;
    const int wave = tid >> 6;
    const int lane = tid & 63;
    const int quad = lane >> 4;
    const int l16  = lane & 15;

    const int hb = blockIdx.x & 15;      // b*8 + h  (XCD L2 locality)
    const int qb = blockIdx.x >> 4;      // 0..31, 64 queries per block
    const int h  = hb & 7;
    const int b  = hb >> 3;
    const int q0 = qb * 64 + wave * 16;  // this wave's 16 queries

    short8 qf[4];
    {
        const bf16* Qbase = qkv + (size_t)(b * 2048 + q0 + l16) * 3072 + h * 128 + quad * 8;
#pragma unroll
        for (int d = 0; d < 4; ++d)
            qf[d] = *(const short8*)(Qbase + d * 32);
    }

    floatx4 Oacc[8];
#pragma unroll
    for (int dt = 0; dt < 8; ++dt)
#pragma unroll
        for (int r = 0; r < 4; ++r) Oacc[dt][r] = 0.0f;
    float psum[4] = {0.0f, 0.0f, 0.0f, 0.0f};

    const int sl = lane & 15;
    const int sq = lane >> 4;
    const bf16* Kbase = qkv + (size_t)b * 2048 * 3072 + 1024 + h * 128;  // +n*3072+d
    const bf16* Vtb   = Vt + (size_t)hb * 128 * 2048;                    // +d*2048+n

    int lo = qb * 64 - 127; if (lo < 0) lo = 0; lo &= ~63;
    int hi = qb * 64 + 63 + 127; if (hi > 2047) hi = 2047;
    const int nchunks = ((hi - lo) >> 6) + 1;

    // this wave's needed key band: [q0-127, q0+15+127]
    const int wlo = q0 - 127;
    const int whi = q0 + 142;

    auto stage = [&](int key0, int buf) {
#pragma unroll
        for (int i = 0; i < 4; ++i) {
            const int tk = wave * 4 + i;
            const int kt = tk >> 2, dc = tk & 3;
            gl_lds16(Kbase + (size_t)(key0 + kt * 16 + sl) * 3072 + dc * 32 + sq * 8,
                     &Kl[buf][0] + tk * 512);
        }
#pragma unroll
        for (int i = 0; i < 4; ++i) {
            const int tv = wave * 4 + i;
            const int dt = tv >> 1, ks = tv & 1;
            gl_lds16(Vtb + (size_t)(dt * 16 + sl) * 2048 + key0 + ks * 32 + sq * 8,
                     &Vl[buf][0] + tv * 512);
        }
    };

    stage(lo, 0);
    for (int t = 0; t < nchunks; ++t) {
        const int key0 = lo + t * 64;
        const int buf  = t & 1;
        __syncthreads();                      // stage(t) complete; prev reads done
        if (t + 1 < nchunks) stage(key0 + 64, buf ^ 1);

        // band skip: chunk entirely outside this wave's window -> P == 0;
        // barriers/staging already issued uniformly above.
        if (key0 + 63 < wlo || key0 > whi) continue;

        floatx4 s[4];
#pragma unroll
        for (int kt = 0; kt < 4; ++kt) {
#pragma unroll
            for (int r = 0; r < 4; ++r) s[kt][r] = 0.0f;
#pragma unroll
            for (int dc = 0; dc < 4; ++dc) {
                short8 kf = *(const short8*)(&Kl[buf][0] + (kt * 4 + dc) * 512 + lane * 8);
                s[kt] = MFMA_BF16(qf[dc], kf, s[kt]);
            }
        }
#pragma unroll
        for (int kt = 0; kt < 4; ++kt) {
#pragma unroll
            for (int r = 0; r < 4; ++r) {
                const int i = q0 + quad * 4 + r;
                const int j = key0 + kt * 16 + l16;
                const bool ok = (unsigned)(i - j + 127) < 255u;  // |i-j| < 128
                const float p = ok ? __expf(s[kt][r] * 0.03125f) : 0.0f;
                psum[r] += p;
                Plds[wave][quad * 4 + r][kt * 16 + l16] = __float2bfloat16(p);
            }
        }
#pragma unroll
        for (int ks = 0; ks < 2; ++ks) {
            short8 pf = *(const short8*)(&Plds[wave][l16][ks * 32 + quad * 8]);
#pragma unroll
            for (int dt = 0; dt < 8; ++dt) {
                short8 vf = *(const short8*)(&Vl[buf][0] + (dt * 2 + ks) * 512 + lane * 8);
                Oacc[dt] = MFMA_BF16(pf, vf, Oacc[dt]);
            }
        }
    }

#pragma unroll
    for (int m = 1; m <= 8; m <<= 1)
#pragma unroll
        for (int r = 0; r < 4; ++r)
            psum[r] += __shfl_xor(psum[r], m, 64);

#pragma unroll
    for (int r = 0; r < 4; ++r) {
        const float inv = 1.0f / psum[r];
        const int row = q0 + quad * 4 + r;
#pragma unroll
        for (int dt = 0; dt < 8; ++dt) {
            out[(size_t)(b * 2048 + row) * 1024 + h * 128 + dt * 16 + l16] =
                __float2bfloat16(Oacc[dt][r] * inv);
        }
    }
}

// ---------------------------------------------------------------------------
extern "C" void kernel_launch(void* const* d_in, const int* in_sizes, int n_in,
                              void* d_out, int out_size, void* d_ws, size_t ws_size,
                              hipStream_t stream)
{
    (void)in_sizes; (void)n_in; (void)out_size; (void)ws_size;

    const void* x      = d_in[0];  // (2, 2048, 1024)  fp32 (or bf16 — sniffed)
    const void* w_qkv  = d_in[1];  // (3072, 1024)
    const void* b_qkv  = d_in[2];  // (3072,)
    const void* w_proj = d_in[3];  // (1024, 1024)
    const void* b_proj = d_in[4];  // (1024,)

    char* ws = (char*)d_ws;
    bf16*  qkv      = (bf16*)(ws);                 // 25,165,824 B  [b][n][3C]
    bf16*  Vt       = (bf16*)(ws + 25165824);      //  8,388,608 B  [b][h][d][n]
    bf16*  attn_out = (bf16*)(ws + 33554432);      //  8,388,608 B  (b,n,c)
    bf16*  xb       = (bf16*)(ws + 41943040);      //  8,388,608 B
    bf16*  wqkvb    = (bf16*)(ws + 50331648);      //  6,291,456 B
    bf16*  wprojb   = (bf16*)(ws + 56623104);      //  2,097,152 B
    float* bqf      = (float*)(ws + 58720256);     //     12,288 B
    float* bpf      = (float*)(ws + 58732544);     //      4,096 B

    // 1) fused input normalization (sniff inlined per block)
    cvt_all_kernel<<<dim3(4100), dim3(256), 0, stream>>>(
        x, w_qkv, w_proj, b_qkv, b_proj, xb, wqkvb, wprojb, bqf, bpf);

    // 2) qkv = x @ w_qkv^T + b_qkv (Q,K -> qkv; V fused-transposed to Vt)
    //    128x128 tile, 8 waves, grid 768 = 3 blocks/CU = 24 waves/CU [R2]
    gemm_bt_kernel<128, 128, 2, 4, 6, true, false>
        <<<dim3(32, 24), dim3(512), 0, stream>>>(
        xb, wqkvb, bqf, qkv, 4096, 3072, 1024, Vt, (const uint16_t*)x);

    // 3) banded attention (v6: band chunk-skip, 2 blocks/CU)
    attn_kernel<<<dim3(512), dim3(256), 0, stream>>>(qkv, Vt, attn_out);

    // 4) out = attn @ w_proj^T + b_proj, output dtype per sniff
    //    128x128 tile, 4 waves (wave 64x64), grid (32,8)=256 with 4 blocks/CU
    //    = 16 waves/CU across 4 independent barrier domains (was 8w x 1)
    gemm_bt_kernel<128, 128, 2, 2, 4, false, true>
        <<<dim3(32, 8), dim3(256), 0, stream>>>(
        attn_out, wprojb, bpf, d_out, 4096, 1024, 1024, nullptr, (const uint16_t*)x);
}

// Round 8
// 158.359 us; speedup vs baseline: 1.0073x; 1.0073x over previous
//
#include <hip/hip_runtime.h>
#include <hip/hip_bf16.h>
#include <stdint.h>

typedef __hip_bfloat16 bf16;
typedef __attribute__((ext_vector_type(8))) short short8;   // 8 bf16 = 4 VGPRs (MFMA A/B frag)
typedef __attribute__((ext_vector_type(4))) float floatx4;  // MFMA C/D frag
typedef __attribute__((ext_vector_type(4))) short s4v;      // 8B bf16 vector store

#define MFMA_BF16(a, b, c) __builtin_amdgcn_mfma_f32_16x16x32_bf16((a), (b), (c), 0, 0, 0)

// Problem constants: B=2, N=2048, C=1024, H=8, D=128, half-window 128.
// qkv workspace layout: [b][n][3*C] with col = which*1024 + h*128 + d
//   (V columns are NOT written to qkv — V lives only in Vt)
// Vt layout: [b][h][d][n]  (PV B-frags contiguous in key)
//
// Session laws (R0-R7):
//  - The 2-barrier template's parameter optimum for ALL kernels is the R2
//    config: GEMM 128^2 / 8 waves; GEMM1 grid 768 (3 blk/CU, 24 w/CU);
//    GEMM2 grid 256. Every deviation lost: smaller tiles (R3: refetch 2x),
//    bigger tiles (R3/R6: occupancy), 4-wave variants (R7: +4.6us),
//    extra barrier domains (R4/R7: null/regress).
//  - GEMM1 schedule-level fixes are null at K=1024 (32 iters): tri-buffer
//    counted-vmcnt (R5) and full 8-phase+T2+T5 (R6: 55.8us, MfmaUtil 17%)
//    both fail to fill their pipelines before the K-loop ends.
//  - GEMM1 memory is NOT the limiter: grid.x=32 = 0 mod 8 makes A-panels
//    XCD-sticky (same bm -> same XCD) -> A refetch is L2-hit; FETCH_SIZE
//    ~29MB ~= one cold pass of A+W.
//  R8 (this round): consolidate to exact R2 + per-kt-tile masking skip in
//    attn (mask-safe: dead kt => ok=false => p=0 regardless of skipped MFMA).

// ---------------------------------------------------------------------------
// async global->LDS 16B copy: LDS dst is wave-uniform (lane i lands at
// dst + i*16 bytes); gsrc is per-lane (arbitrary gather). [m97/m104-verified]
// ---------------------------------------------------------------------------
__device__ __forceinline__ void gl_lds16(const bf16* gsrc, bf16* lds_dst)
{
    __builtin_amdgcn_global_load_lds(
        (const __attribute__((address_space(1))) uint32_t*)(uintptr_t)gsrc,
        (__attribute__((address_space(3))) uint32_t*)(uintptr_t)lds_dst,
        16, 0, 0);
}

// ---------------------------------------------------------------------------
// Dtype sniff: bf16 N(0,1) halfword[2i] has exponent in [100,140] ~always;
// fp32 low-mantissa halfwords hit that band ~16%.
// ---------------------------------------------------------------------------
__device__ __forceinline__ int sniff_bf16(const uint16_t* __restrict__ x)
{
    int cnt = 0;
#pragma unroll
    for (int i = 0; i < 64; ++i) {
        const int e = (x[2 * i] >> 7) & 0xFF;
        cnt += (e >= 100 && e <= 140) ? 1 : 0;
    }
    return (cnt >= 32) ? 1 : 0;
}

// ---------------------------------------------------------------------------
// One fused conversion kernel: x / w_qkv / w_proj -> bf16 (8 elems/thread),
// biases -> fp32. Grid = 4100 blocks x 256.
// ---------------------------------------------------------------------------
__global__ void __launch_bounds__(256)
cvt_all_kernel(const void* __restrict__ x, const void* __restrict__ wq,
               const void* __restrict__ wp, const void* __restrict__ bq,
               const void* __restrict__ bp,
               bf16* __restrict__ xb, bf16* __restrict__ wqb,
               bf16* __restrict__ wpb, float* __restrict__ bqf,
               float* __restrict__ bpf)
{
    __shared__ int sflag;
    if (threadIdx.x == 0) sflag = sniff_bf16((const uint16_t*)x);
    __syncthreads();
    const bool isbf = (sflag != 0);

    const int blk = blockIdx.x;
    if (blk < 4096) {
        const void* src; bf16* dst; int base;
        if (blk < 2048)      { src = x;  dst = xb;  base = blk << 11; }
        else if (blk < 3584) { src = wq; dst = wqb; base = (blk - 2048) << 11; }
        else                 { src = wp; dst = wpb; base = (blk - 3584) << 11; }
        const int i = base + (int)threadIdx.x * 8;
        if (isbf) {
            *(uint4*)(dst + i) = *(const uint4*)((const bf16*)src + i);
        } else {
            const float4 f0 = *(const float4*)((const float*)src + i);
            const float4 f1 = *(const float4*)((const float*)src + i + 4);
            bf16 o[8];
            o[0] = __float2bfloat16(f0.x); o[1] = __float2bfloat16(f0.y);
            o[2] = __float2bfloat16(f0.z); o[3] = __float2bfloat16(f0.w);
            o[4] = __float2bfloat16(f1.x); o[5] = __float2bfloat16(f1.y);
            o[6] = __float2bfloat16(f1.z); o[7] = __float2bfloat16(f1.w);
            *(uint4*)(dst + i) = *(uint4*)o;
        }
    } else {
        const void* src; float* dst; int base, n;
        if (blk < 4099) { src = bq; dst = bqf; base = (blk - 4096) * 1024; n = 3072; }
        else            { src = bp; dst = bpf; base = 0;                   n = 1024; }
        const int i0 = base + (int)threadIdx.x * 4;
#pragma unroll
        for (int k = 0; k < 4; ++k) {
            const int idx = i0 + k;
            if (idx < n)
                dst[idx] = isbf ? __bfloat162float(((const bf16*)src)[idx])
                                : ((const float*)src)[idx];
        }
    }
}

// ---------------------------------------------------------------------------
// GEMM: C[m,n] = sum_k A[m,k] * W[n,k] + bias[n]   (x @ W^T + b, W row-major)
// Parameterized 2-barrier dbuf template. BK=32. Waves form a WROWS x WCOLS
// grid; wave tile = (BM/WROWS) x (BN/WCOLS); acc = (WTM/16) x (WTN/16).
//
// Configs (R8 = exact R2 optimum):
//   GEMM1: 128x128, 8 waves (2x4), wave 64x32, grid (32,24)=768
//          = 3 blocks/CU = 24 waves/CU.
//   GEMM2: 128x128, 8 waves (2x4), wave 64x32, grid (32,8)=256.
// FUSE_VT epilogue: V cols (>=2048) go ONLY to Vt (8B vector stores);
// 2048 is a multiple of 16 so the branch is uniform per 16-col frag.
// ---------------------------------------------------------------------------
template <int BM, int BN, int WROWS, int WCOLS, int MINW, bool FUSE_VT, bool DYN_OUT>
__global__ void __launch_bounds__(WROWS* WCOLS * 64, MINW)
gemm_bt_kernel(const bf16* __restrict__ A, const bf16* __restrict__ W,
               const float* __restrict__ bias, void* __restrict__ Cout,
               int M, int Nc, int K, bf16* __restrict__ Vt,
               const uint16_t* __restrict__ sniffsrc)
{
    constexpr int WAVES  = WROWS * WCOLS;
    constexpr int WTM    = BM / WROWS;
    constexpr int WTN    = BN / WCOLS;
    constexpr int AI     = WTM / 16;
    constexpr int AJ     = WTN / 16;
    constexpr int ASHOTS = BM / 16;          // 1 KB staging shots (16 rows)
    constexpr int TSHOTS = (BM + BN) / 16;

    __shared__ __align__(16) bf16 As[2][BM][32];
    __shared__ __align__(16) bf16 Bs[2][BN][32];
    __shared__ int sflag;

    const int tid  = threadIdx.x;
    const int lane = tid & 63;
    const int wave = tid >> 6;
    const int quad = lane >> 4;
    const int l16  = lane & 15;
    const int wm   = (wave % WROWS) * WTM;
    const int wn   = (wave / WROWS) * WTN;
    const int bm   = blockIdx.x * BM;
    const int bn   = blockIdx.y * BN;

    if (DYN_OUT && tid == 0) sflag = sniff_bf16(sniffsrc);

    // staging: shot s = 16 rows x 32 cols (1 KB); lane -> row lane>>2,
    // 16B col chunk lane&3. Shots round-robin over waves.
    const int srow = lane >> 2;
    const int scol = (lane & 3) * 8;
    const bf16* Abase = A + (size_t)(bm + srow) * K + scol;
    const bf16* Wbase = W + (size_t)(bn + srow) * K + scol;

    floatx4 acc[AI][AJ];
#pragma unroll
    for (int i = 0; i < AI; ++i)
#pragma unroll
        for (int j = 0; j < AJ; ++j)
#pragma unroll
            for (int r = 0; r < 4; ++r) acc[i][j][r] = 0.0f;

    auto stage = [&](int k0, int buf) {
#pragma unroll
        for (int s = wave; s < TSHOTS; s += WAVES) {
            if (s < ASHOTS) {
                gl_lds16(Abase + (size_t)(s * 16) * K + k0,
                         &As[buf][0][0] + s * 512);
            } else {
                const int t = s - ASHOTS;
                gl_lds16(Wbase + (size_t)(t * 16) * K + k0,
                         &Bs[buf][0][0] + t * 512);
            }
        }
    };

    stage(0, 0);
    const int niter = K >> 5;
    for (int it = 0; it < niter; ++it) {
        const int buf = it & 1;
        __syncthreads();                       // stage(it) complete; prev reads done
        if (it + 1 < niter) stage((it + 1) << 5, buf ^ 1);

        short8 af[AI], bfr[AJ];
#pragma unroll
        for (int i = 0; i < AI; ++i)
            af[i] = *(const short8*)(&As[buf][wm + i * 16 + l16][quad * 8]);
#pragma unroll
        for (int j = 0; j < AJ; ++j)
            bfr[j] = *(const short8*)(&Bs[buf][wn + j * 16 + l16][quad * 8]);
#pragma unroll
        for (int i = 0; i < AI; ++i)
#pragma unroll
            for (int j = 0; j < AJ; ++j)
                acc[i][j] = MFMA_BF16(af[i], bfr[j], acc[i][j]);
    }

    const bool outbf = DYN_OUT ? (sflag != 0) : true;

    // epilogue: C/D layout row = quad*4+r, col = l16
#pragma unroll
    for (int i = 0; i < AI; ++i) {
#pragma unroll
        for (int j = 0; j < AJ; ++j) {
            const int col = bn + wn + j * 16 + l16;
            const float bv = bias[col];
            if (FUSE_VT && col >= 2048) {
                // V columns: transposed store to Vt only (8B vector store;
                // rows quad*4 + r are consecutive nn in Vt's last dim)
                const int hh   = (col - 2048) >> 7;
                const int dd   = (col - 2048) & 127;
                const int row0 = bm + wm + i * 16 + quad * 4;
                const int bb   = row0 >> 11;     // M = 4096 = B*N
                const int nn   = row0 & 2047;
                __align__(8) bf16 vv[4];
#pragma unroll
                for (int r = 0; r < 4; ++r)
                    vv[r] = __float2bfloat16(acc[i][j][r] + bv);
                *(s4v*)(Vt + (((size_t)bb * 8 + hh) * 128 + dd) * 2048 + nn) =
                    *(const s4v*)vv;
            } else {
#pragma unroll
                for (int r = 0; r < 4; ++r) {
                    const int row = bm + wm + i * 16 + quad * 4 + r;
                    const float v = acc[i][j][r] + bv;
                    const size_t idx = (size_t)row * Nc + col;
                    if (!DYN_OUT || outbf) {
                        ((bf16*)Cout)[idx] = __float2bfloat16(v);
                    } else {
                        ((float*)Cout)[idx] = v;
                    }
                }
            }
        }
    }
}

// ---------------------------------------------------------------------------
// Banded attention v7 = v6 + per-kt-tile masking skip. 4 waves / 64 queries;
// K/V staged in MFMA B-frag order, dbuf single-barrier pipeline; wave-private
// Plds; shift-free softmax; XCD swizzle; chunk-skip. Grid 512 -> 2 blk/CU.
//
// New: within a live chunk, kt-tiles (16 keys) outside this wave's band are
// skipped in QK^T (4 ds_read + 4 MFMA) and exp; Plds is explicitly zeroed
// for them so PV stays correct; a PV ks-half whose BOTH kt-tiles are dead is
// skipped entirely (9 reads + 8 MFMA). All guards wave-uniform.
// Mask-safety: dead kt => ok=false for every lane => p=0 regardless of s.
// For interior q-blocks chunk-skip catches nothing (every chunk has a live
// tile) while ~3/20 kt-tiles per wave are dead -> ~15% QK / ~10% PV saved.
// ---------------------------------------------------------------------------
__global__ void __launch_bounds__(256, 2)
attn_kernel(const bf16* __restrict__ qkv, const bf16* __restrict__ Vt,
            bf16* __restrict__ out)
{
    __shared__ __align__(16) bf16 Kl[2][16 * 512];   // 32 KB, frag-ordered
    __shared__ __align__(16) bf16 Vl[2][16 * 512];   // 32 KB, frag-ordered
    __shared__ __align__(16) bf16 Plds[4][16][72];   // 9.2 KB, wave-private P

    const int tid  = threadIdx.x;
    const int wave = tid >> 6;
    const int lane = tid & 63;
    const int quad = lane >> 4;
    const int l16  = lane & 15;

    const int hb = blockIdx.x & 15;      // b*8 + h  (XCD L2 locality)
    const int qb = blockIdx.x >> 4;      // 0..31, 64 queries per block
    const int h  = hb & 7;
    const int b  = hb >> 3;
    const int q0 = qb * 64 + wave * 16;  // this wave's 16 queries

    short8 qf[4];
    {
        const bf16* Qbase = qkv + (size_t)(b * 2048 + q0 + l16) * 3072 + h * 128 + quad * 8;
#pragma unroll
        for (int d = 0; d < 4; ++d)
            qf[d] = *(const short8*)(Qbase + d * 32);
    }

    floatx4 Oacc[8];
#pragma unroll
    for (int dt = 0; dt < 8; ++dt)
#pragma unroll
        for (int r = 0; r < 4; ++r) Oacc[dt][r] = 0.0f;
    float psum[4] = {0.0f, 0.0f, 0.0f, 0.0f};

    const int sl = lane & 15;
    const int sq = lane >> 4;
    const bf16* Kbase = qkv + (size_t)b * 2048 * 3072 + 1024 + h * 128;  // +n*3072+d
    const bf16* Vtb   = Vt + (size_t)hb * 128 * 2048;                    // +d*2048+n

    int lo = qb * 64 - 127; if (lo < 0) lo = 0; lo &= ~63;
    int hi = qb * 64 + 63 + 127; if (hi > 2047) hi = 2047;
    const int nchunks = ((hi - lo) >> 6) + 1;

    // this wave's needed key band: [q0-127, q0+15+127]
    const int wlo = q0 - 127;
    const int whi = q0 + 142;

    auto stage = [&](int key0, int buf) {
#pragma unroll
        for (int i = 0; i < 4; ++i) {
            const int tk = wave * 4 + i;
            const int kt = tk >> 2, dc = tk & 3;
            gl_lds16(Kbase + (size_t)(key0 + kt * 16 + sl) * 3072 + dc * 32 + sq * 8,
                     &Kl[buf][0] + tk * 512);
        }
#pragma unroll
        for (int i = 0; i < 4; ++i) {
            const int tv = wave * 4 + i;
            const int dt = tv >> 1, ks = tv & 1;
            gl_lds16(Vtb + (size_t)(dt * 16 + sl) * 2048 + key0 + ks * 32 + sq * 8,
                     &Vl[buf][0] + tv * 512);
        }
    };

    stage(lo, 0);
    for (int t = 0; t < nchunks; ++t) {
        const int key0 = lo + t * 64;
        const int buf  = t & 1;
        __syncthreads();                      // stage(t) complete; prev reads done
        if (t + 1 < nchunks) stage(key0 + 64, buf ^ 1);

        // chunk skip: entirely outside this wave's window -> P == 0;
        // barriers/staging already issued uniformly above.
        if (key0 + 63 < wlo || key0 > whi) continue;

        // per-kt-tile liveness (wave-uniform)
        bool ktl[4];
#pragma unroll
        for (int kt = 0; kt < 4; ++kt) {
            const int k0t = key0 + kt * 16;
            ktl[kt] = (k0t + 15 >= wlo) && (k0t <= whi);
        }

        floatx4 s[4];
#pragma unroll
        for (int kt = 0; kt < 4; ++kt) {
#pragma unroll
            for (int r = 0; r < 4; ++r) s[kt][r] = 0.0f;
            if (ktl[kt]) {
#pragma unroll
                for (int dc = 0; dc < 4; ++dc) {
                    short8 kf = *(const short8*)(&Kl[buf][0] + (kt * 4 + dc) * 512 + lane * 8);
                    s[kt] = MFMA_BF16(qf[dc], kf, s[kt]);
                }
            }
        }
#pragma unroll
        for (int kt = 0; kt < 4; ++kt) {
            if (ktl[kt]) {
#pragma unroll
                for (int r = 0; r < 4; ++r) {
                    const int i = q0 + quad * 4 + r;
                    const int j = key0 + kt * 16 + l16;
                    const bool ok = (unsigned)(i - j + 127) < 255u;  // |i-j| < 128
                    const float p = ok ? __expf(s[kt][r] * 0.03125f) : 0.0f;
                    psum[r] += p;
                    Plds[wave][quad * 4 + r][kt * 16 + l16] = __float2bfloat16(p);
                }
            } else {
                // dead tile: zero P half so PV (if its half is live) is correct
#pragma unroll
                for (int r = 0; r < 4; ++r)
                    Plds[wave][quad * 4 + r][kt * 16 + l16] = __float2bfloat16(0.0f);
            }
        }
#pragma unroll
        for (int ks = 0; ks < 2; ++ks) {
            if (!(ktl[2 * ks] || ktl[2 * ks + 1])) continue;  // P half all-zero
            short8 pf = *(const short8*)(&Plds[wave][l16][ks * 32 + quad * 8]);
#pragma unroll
            for (int dt = 0; dt < 8; ++dt) {
                short8 vf = *(const short8*)(&Vl[buf][0] + (dt * 2 + ks) * 512 + lane * 8);
                Oacc[dt] = MFMA_BF16(pf, vf, Oacc[dt]);
            }
        }
    }

#pragma unroll
    for (int m = 1; m <= 8; m <<= 1)
#pragma unroll
        for (int r = 0; r < 4; ++r)
            psum[r] += __shfl_xor(psum[r], m, 64);

#pragma unroll
    for (int r = 0; r < 4; ++r) {
        const float inv = 1.0f / psum[r];
        const int row = q0 + quad * 4 + r;
#pragma unroll
        for (int dt = 0; dt < 8; ++dt) {
            out[(size_t)(b * 2048 + row) * 1024 + h * 128 + dt * 16 + l16] =
                __float2bfloat16(Oacc[dt][r] * inv);
        }
    }
}

// ---------------------------------------------------------------------------
extern "C" void kernel_launch(void* const* d_in, const int* in_sizes, int n_in,
                              void* d_out, int out_size, void* d_ws, size_t ws_size,
                              hipStream_t stream)
{
    (void)in_sizes; (void)n_in; (void)out_size; (void)ws_size;

    const void* x      = d_in[0];  // (2, 2048, 1024)  fp32 (or bf16 — sniffed)
    const void* w_qkv  = d_in[1];  // (3072, 1024)
    const void* b_qkv  = d_in[2];  // (3072,)
    const void* w_proj = d_in[3];  // (1024, 1024)
    const void* b_proj = d_in[4];  // (1024,)

    char* ws = (char*)d_ws;
    bf16*  qkv      = (bf16*)(ws);                 // 25,165,824 B  [b][n][3C]
    bf16*  Vt       = (bf16*)(ws + 25165824);      //  8,388,608 B  [b][h][d][n]
    bf16*  attn_out = (bf16*)(ws + 33554432);      //  8,388,608 B  (b,n,c)
    bf16*  xb       = (bf16*)(ws + 41943040);      //  8,388,608 B
    bf16*  wqkvb    = (bf16*)(ws + 50331648);      //  6,291,456 B
    bf16*  wprojb   = (bf16*)(ws + 56623104);      //  2,097,152 B
    float* bqf      = (float*)(ws + 58720256);     //     12,288 B
    float* bpf      = (float*)(ws + 58732544);     //      4,096 B

    // 1) fused input normalization (sniff inlined per block)
    cvt_all_kernel<<<dim3(4100), dim3(256), 0, stream>>>(
        x, w_qkv, w_proj, b_qkv, b_proj, xb, wqkvb, wprojb, bqf, bpf);

    // 2) qkv = x @ w_qkv^T + b_qkv (Q,K -> qkv; V fused-transposed to Vt)
    //    128x128 tile, 8 waves, grid 768 = 3 blocks/CU = 24 waves/CU [R2]
    gemm_bt_kernel<128, 128, 2, 4, 6, true, false>
        <<<dim3(32, 24), dim3(512), 0, stream>>>(
        xb, wqkvb, bqf, qkv, 4096, 3072, 1024, Vt, (const uint16_t*)x);

    // 3) banded attention (v7: chunk-skip + per-kt masking skip, 2 blk/CU)
    attn_kernel<<<dim3(512), dim3(256), 0, stream>>>(qkv, Vt, attn_out);

    // 4) out = attn @ w_proj^T + b_proj, output dtype per sniff
    //    128x128 tile, 8 waves, grid (32,8)=256  [R2-proven config]
    gemm_bt_kernel<128, 128, 2, 4, 6, false, true>
        <<<dim3(32, 8), dim3(512), 0, stream>>>(
        attn_out, wprojb, bpf, d_out, 4096, 1024, 1024, nullptr, (const uint16_t*)x);
}

// Round 9
// 154.460 us; speedup vs baseline: 1.0328x; 1.0252x over previous
//
#include <hip/hip_runtime.h>
#include <hip/hip_bf16.h>
#include <stdint.h>

typedef __hip_bfloat16 bf16;
typedef __attribute__((ext_vector_type(8))) short short8;   // 8 bf16 = 4 VGPRs (MFMA A/B frag)
typedef __attribute__((ext_vector_type(4))) float floatx4;  // MFMA C/D frag
typedef __attribute__((ext_vector_type(4))) short s4v;      // 8B bf16 vector store

#define MFMA_BF16(a, b, c) __builtin_amdgcn_mfma_f32_16x16x32_bf16((a), (b), (c), 0, 0, 0)

// Problem constants: B=2, N=2048, C=1024, H=8, D=128, half-window 128.
// qkv workspace layout: [b][n][3*C] with col = which*1024 + h*128 + d
//   (V columns are NOT written to qkv — V lives only in Vt)
// Vt layout: [b][h][d][n]  (PV B-frags contiguous in key)
//
// Session laws (R0-R8) — final consolidated state = exact R2 optimum:
//  - 2-barrier template parameter optimum: GEMM 128^2 / 8 waves; GEMM1
//    grid 768 (3 blk/CU, 24 w/CU); GEMM2 grid 256. Deviations lost:
//    smaller tiles (R3: 2x refetch), bigger tiles (R3/R6), 4-wave variants
//    (R7: +4.6us), extra barrier domains (R4/R7).
//  - GEMM1 schedule-level fixes null at K=1024 (32 iters): tri-buffer
//    counted-vmcnt (R5), full 8-phase+T2+T4+T5 (R6: 55.8us, MfmaUtil 17% —
//    pipeline never fills in 16 K-tiles at 2 waves/SIMD).
//  - attn per-kt-tile skip (R8): regression (+3.5us) — guards broke the
//    flat MFMA schedule; chunk-level skip (v6) is the right granularity.
//  - GEMM1 memory is NOT the limiter (A panels XCD-sticky, FETCH ~ one
//    cold pass); it is at its structural plateau ~52us across 3 families.

// ---------------------------------------------------------------------------
// async global->LDS 16B copy: LDS dst is wave-uniform (lane i lands at
// dst + i*16 bytes); gsrc is per-lane (arbitrary gather). [m97/m104-verified]
// ---------------------------------------------------------------------------
__device__ __forceinline__ void gl_lds16(const bf16* gsrc, bf16* lds_dst)
{
    __builtin_amdgcn_global_load_lds(
        (const __attribute__((address_space(1))) uint32_t*)(uintptr_t)gsrc,
        (__attribute__((address_space(3))) uint32_t*)(uintptr_t)lds_dst,
        16, 0, 0);
}

// ---------------------------------------------------------------------------
// Dtype sniff: bf16 N(0,1) halfword[2i] has exponent in [100,140] ~always;
// fp32 low-mantissa halfwords hit that band ~16%.
// ---------------------------------------------------------------------------
__device__ __forceinline__ int sniff_bf16(const uint16_t* __restrict__ x)
{
    int cnt = 0;
#pragma unroll
    for (int i = 0; i < 64; ++i) {
        const int e = (x[2 * i] >> 7) & 0xFF;
        cnt += (e >= 100 && e <= 140) ? 1 : 0;
    }
    return (cnt >= 32) ? 1 : 0;
}

// ---------------------------------------------------------------------------
// One fused conversion kernel: x / w_qkv / w_proj -> bf16 (8 elems/thread),
// biases -> fp32. Grid = 4100 blocks x 256.
// ---------------------------------------------------------------------------
__global__ void __launch_bounds__(256)
cvt_all_kernel(const void* __restrict__ x, const void* __restrict__ wq,
               const void* __restrict__ wp, const void* __restrict__ bq,
               const void* __restrict__ bp,
               bf16* __restrict__ xb, bf16* __restrict__ wqb,
               bf16* __restrict__ wpb, float* __restrict__ bqf,
               float* __restrict__ bpf)
{
    __shared__ int sflag;
    if (threadIdx.x == 0) sflag = sniff_bf16((const uint16_t*)x);
    __syncthreads();
    const bool isbf = (sflag != 0);

    const int blk = blockIdx.x;
    if (blk < 4096) {
        const void* src; bf16* dst; int base;
        if (blk < 2048)      { src = x;  dst = xb;  base = blk << 11; }
        else if (blk < 3584) { src = wq; dst = wqb; base = (blk - 2048) << 11; }
        else                 { src = wp; dst = wpb; base = (blk - 3584) << 11; }
        const int i = base + (int)threadIdx.x * 8;
        if (isbf) {
            *(uint4*)(dst + i) = *(const uint4*)((const bf16*)src + i);
        } else {
            const float4 f0 = *(const float4*)((const float*)src + i);
            const float4 f1 = *(const float4*)((const float*)src + i + 4);
            bf16 o[8];
            o[0] = __float2bfloat16(f0.x); o[1] = __float2bfloat16(f0.y);
            o[2] = __float2bfloat16(f0.z); o[3] = __float2bfloat16(f0.w);
            o[4] = __float2bfloat16(f1.x); o[5] = __float2bfloat16(f1.y);
            o[6] = __float2bfloat16(f1.z); o[7] = __float2bfloat16(f1.w);
            *(uint4*)(dst + i) = *(uint4*)o;
        }
    } else {
        const void* src; float* dst; int base, n;
        if (blk < 4099) { src = bq; dst = bqf; base = (blk - 4096) * 1024; n = 3072; }
        else            { src = bp; dst = bpf; base = 0;                   n = 1024; }
        const int i0 = base + (int)threadIdx.x * 4;
#pragma unroll
        for (int k = 0; k < 4; ++k) {
            const int idx = i0 + k;
            if (idx < n)
                dst[idx] = isbf ? __bfloat162float(((const bf16*)src)[idx])
                                : ((const float*)src)[idx];
        }
    }
}

// ---------------------------------------------------------------------------
// GEMM: C[m,n] = sum_k A[m,k] * W[n,k] + bias[n]   (x @ W^T + b, W row-major)
// Parameterized 2-barrier dbuf template. BK=32. Waves form a WROWS x WCOLS
// grid; wave tile = (BM/WROWS) x (BN/WCOLS); acc = (WTM/16) x (WTN/16).
//
// Configs (final = exact R2 optimum):
//   GEMM1: 128x128, 8 waves (2x4), wave 64x32, grid (32,24)=768
//          = 3 blocks/CU = 24 waves/CU.
//   GEMM2: 128x128, 8 waves (2x4), wave 64x32, grid (32,8)=256.
// FUSE_VT epilogue: V cols (>=2048) go ONLY to Vt (8B vector stores);
// 2048 is a multiple of 16 so the branch is uniform per 16-col frag.
// ---------------------------------------------------------------------------
template <int BM, int BN, int WROWS, int WCOLS, int MINW, bool FUSE_VT, bool DYN_OUT>
__global__ void __launch_bounds__(WROWS* WCOLS * 64, MINW)
gemm_bt_kernel(const bf16* __restrict__ A, const bf16* __restrict__ W,
               const float* __restrict__ bias, void* __restrict__ Cout,
               int M, int Nc, int K, bf16* __restrict__ Vt,
               const uint16_t* __restrict__ sniffsrc)
{
    constexpr int WAVES  = WROWS * WCOLS;
    constexpr int WTM    = BM / WROWS;
    constexpr int WTN    = BN / WCOLS;
    constexpr int AI     = WTM / 16;
    constexpr int AJ     = WTN / 16;
    constexpr int ASHOTS = BM / 16;          // 1 KB staging shots (16 rows)
    constexpr int TSHOTS = (BM + BN) / 16;

    __shared__ __align__(16) bf16 As[2][BM][32];
    __shared__ __align__(16) bf16 Bs[2][BN][32];
    __shared__ int sflag;

    const int tid  = threadIdx.x;
    const int lane = tid & 63;
    const int wave = tid >> 6;
    const int quad = lane >> 4;
    const int l16  = lane & 15;
    const int wm   = (wave % WROWS) * WTM;
    const int wn   = (wave / WROWS) * WTN;
    const int bm   = blockIdx.x * BM;
    const int bn   = blockIdx.y * BN;

    if (DYN_OUT && tid == 0) sflag = sniff_bf16(sniffsrc);

    // staging: shot s = 16 rows x 32 cols (1 KB); lane -> row lane>>2,
    // 16B col chunk lane&3. Shots round-robin over waves.
    const int srow = lane >> 2;
    const int scol = (lane & 3) * 8;
    const bf16* Abase = A + (size_t)(bm + srow) * K + scol;
    const bf16* Wbase = W + (size_t)(bn + srow) * K + scol;

    floatx4 acc[AI][AJ];
#pragma unroll
    for (int i = 0; i < AI; ++i)
#pragma unroll
        for (int j = 0; j < AJ; ++j)
#pragma unroll
            for (int r = 0; r < 4; ++r) acc[i][j][r] = 0.0f;

    auto stage = [&](int k0, int buf) {
#pragma unroll
        for (int s = wave; s < TSHOTS; s += WAVES) {
            if (s < ASHOTS) {
                gl_lds16(Abase + (size_t)(s * 16) * K + k0,
                         &As[buf][0][0] + s * 512);
            } else {
                const int t = s - ASHOTS;
                gl_lds16(Wbase + (size_t)(t * 16) * K + k0,
                         &Bs[buf][0][0] + t * 512);
            }
        }
    };

    stage(0, 0);
    const int niter = K >> 5;
    for (int it = 0; it < niter; ++it) {
        const int buf = it & 1;
        __syncthreads();                       // stage(it) complete; prev reads done
        if (it + 1 < niter) stage((it + 1) << 5, buf ^ 1);

        short8 af[AI], bfr[AJ];
#pragma unroll
        for (int i = 0; i < AI; ++i)
            af[i] = *(const short8*)(&As[buf][wm + i * 16 + l16][quad * 8]);
#pragma unroll
        for (int j = 0; j < AJ; ++j)
            bfr[j] = *(const short8*)(&Bs[buf][wn + j * 16 + l16][quad * 8]);
#pragma unroll
        for (int i = 0; i < AI; ++i)
#pragma unroll
            for (int j = 0; j < AJ; ++j)
                acc[i][j] = MFMA_BF16(af[i], bfr[j], acc[i][j]);
    }

    const bool outbf = DYN_OUT ? (sflag != 0) : true;

    // epilogue: C/D layout row = quad*4+r, col = l16
#pragma unroll
    for (int i = 0; i < AI; ++i) {
#pragma unroll
        for (int j = 0; j < AJ; ++j) {
            const int col = bn + wn + j * 16 + l16;
            const float bv = bias[col];
            if (FUSE_VT && col >= 2048) {
                // V columns: transposed store to Vt only (8B vector store;
                // rows quad*4 + r are consecutive nn in Vt's last dim)
                const int hh   = (col - 2048) >> 7;
                const int dd   = (col - 2048) & 127;
                const int row0 = bm + wm + i * 16 + quad * 4;
                const int bb   = row0 >> 11;     // M = 4096 = B*N
                const int nn   = row0 & 2047;
                __align__(8) bf16 vv[4];
#pragma unroll
                for (int r = 0; r < 4; ++r)
                    vv[r] = __float2bfloat16(acc[i][j][r] + bv);
                *(s4v*)(Vt + (((size_t)bb * 8 + hh) * 128 + dd) * 2048 + nn) =
                    *(const s4v*)vv;
            } else {
#pragma unroll
                for (int r = 0; r < 4; ++r) {
                    const int row = bm + wm + i * 16 + quad * 4 + r;
                    const float v = acc[i][j][r] + bv;
                    const size_t idx = (size_t)row * Nc + col;
                    if (!DYN_OUT || outbf) {
                        ((bf16*)Cout)[idx] = __float2bfloat16(v);
                    } else {
                        ((float*)Cout)[idx] = v;
                    }
                }
            }
        }
    }
}

// ---------------------------------------------------------------------------
// Banded attention v6 (R2-verified optimum): 4 waves / 64 queries; K/V staged
// in MFMA B-frag order, dbuf single-barrier pipeline; wave-private Plds;
// shift-free softmax; XCD swizzle; per-wave band chunk-skip (chunk
// granularity only — per-kt skip regressed in R8). Grid 512 -> 2 blk/CU.
// ---------------------------------------------------------------------------
__global__ void __launch_bounds__(256, 2)
attn_kernel(const bf16* __restrict__ qkv, const bf16* __restrict__ Vt,
            bf16* __restrict__ out)
{
    __shared__ __align__(16) bf16 Kl[2][16 * 512];   // 32 KB, frag-ordered
    __shared__ __align__(16) bf16 Vl[2][16 * 512];   // 32 KB, frag-ordered
    __shared__ __align__(16) bf16 Plds[4][16][72];   // 9.2 KB, wave-private P

    const int tid  = threadIdx.x;
    const int wave = tid >> 6;
    const int lane = tid & 63;
    const int quad = lane >> 4;
    const int l16  = lane & 15;

    const int hb = blockIdx.x & 15;      // b*8 + h  (XCD L2 locality)
    const int qb = blockIdx.x >> 4;      // 0..31, 64 queries per block
    const int h  = hb & 7;
    const int b  = hb >> 3;
    const int q0 = qb * 64 + wave * 16;  // this wave's 16 queries

    short8 qf[4];
    {
        const bf16* Qbase = qkv + (size_t)(b * 2048 + q0 + l16) * 3072 + h * 128 + quad * 8;
#pragma unroll
        for (int d = 0; d < 4; ++d)
            qf[d] = *(const short8*)(Qbase + d * 32);
    }

    floatx4 Oacc[8];
#pragma unroll
    for (int dt = 0; dt < 8; ++dt)
#pragma unroll
        for (int r = 0; r < 4; ++r) Oacc[dt][r] = 0.0f;
    float psum[4] = {0.0f, 0.0f, 0.0f, 0.0f};

    const int sl = lane & 15;
    const int sq = lane >> 4;
    const bf16* Kbase = qkv + (size_t)b * 2048 * 3072 + 1024 + h * 128;  // +n*3072+d
    const bf16* Vtb   = Vt + (size_t)hb * 128 * 2048;                    // +d*2048+n

    int lo = qb * 64 - 127; if (lo < 0) lo = 0; lo &= ~63;
    int hi = qb * 64 + 63 + 127; if (hi > 2047) hi = 2047;
    const int nchunks = ((hi - lo) >> 6) + 1;

    // this wave's needed key band: [q0-127, q0+15+127]
    const int wlo = q0 - 127;
    const int whi = q0 + 142;

    auto stage = [&](int key0, int buf) {
#pragma unroll
        for (int i = 0; i < 4; ++i) {
            const int tk = wave * 4 + i;
            const int kt = tk >> 2, dc = tk & 3;
            gl_lds16(Kbase + (size_t)(key0 + kt * 16 + sl) * 3072 + dc * 32 + sq * 8,
                     &Kl[buf][0] + tk * 512);
        }
#pragma unroll
        for (int i = 0; i < 4; ++i) {
            const int tv = wave * 4 + i;
            const int dt = tv >> 1, ks = tv & 1;
            gl_lds16(Vtb + (size_t)(dt * 16 + sl) * 2048 + key0 + ks * 32 + sq * 8,
                     &Vl[buf][0] + tv * 512);
        }
    };

    stage(lo, 0);
    for (int t = 0; t < nchunks; ++t) {
        const int key0 = lo + t * 64;
        const int buf  = t & 1;
        __syncthreads();                      // stage(t) complete; prev reads done
        if (t + 1 < nchunks) stage(key0 + 64, buf ^ 1);

        // band skip: chunk entirely outside this wave's window -> P == 0;
        // barriers/staging already issued uniformly above.
        if (key0 + 63 < wlo || key0 > whi) continue;

        floatx4 s[4];
#pragma unroll
        for (int kt = 0; kt < 4; ++kt) {
#pragma unroll
            for (int r = 0; r < 4; ++r) s[kt][r] = 0.0f;
#pragma unroll
            for (int dc = 0; dc < 4; ++dc) {
                short8 kf = *(const short8*)(&Kl[buf][0] + (kt * 4 + dc) * 512 + lane * 8);
                s[kt] = MFMA_BF16(qf[dc], kf, s[kt]);
            }
        }
#pragma unroll
        for (int kt = 0; kt < 4; ++kt) {
#pragma unroll
            for (int r = 0; r < 4; ++r) {
                const int i = q0 + quad * 4 + r;
                const int j = key0 + kt * 16 + l16;
                const bool ok = (unsigned)(i - j + 127) < 255u;  // |i-j| < 128
                const float p = ok ? __expf(s[kt][r] * 0.03125f) : 0.0f;
                psum[r] += p;
                Plds[wave][quad * 4 + r][kt * 16 + l16] = __float2bfloat16(p);
            }
        }
#pragma unroll
        for (int ks = 0; ks < 2; ++ks) {
            short8 pf = *(const short8*)(&Plds[wave][l16][ks * 32 + quad * 8]);
#pragma unroll
            for (int dt = 0; dt < 8; ++dt) {
                short8 vf = *(const short8*)(&Vl[buf][0] + (dt * 2 + ks) * 512 + lane * 8);
                Oacc[dt] = MFMA_BF16(pf, vf, Oacc[dt]);
            }
        }
    }

#pragma unroll
    for (int m = 1; m <= 8; m <<= 1)
#pragma unroll
        for (int r = 0; r < 4; ++r)
            psum[r] += __shfl_xor(psum[r], m, 64);

#pragma unroll
    for (int r = 0; r < 4; ++r) {
        const float inv = 1.0f / psum[r];
        const int row = q0 + quad * 4 + r;
#pragma unroll
        for (int dt = 0; dt < 8; ++dt) {
            out[(size_t)(b * 2048 + row) * 1024 + h * 128 + dt * 16 + l16] =
                __float2bfloat16(Oacc[dt][r] * inv);
        }
    }
}

// ---------------------------------------------------------------------------
extern "C" void kernel_launch(void* const* d_in, const int* in_sizes, int n_in,
                              void* d_out, int out_size, void* d_ws, size_t ws_size,
                              hipStream_t stream)
{
    (void)in_sizes; (void)n_in; (void)out_size; (void)ws_size;

    const void* x      = d_in[0];  // (2, 2048, 1024)  fp32 (or bf16 — sniffed)
    const void* w_qkv  = d_in[1];  // (3072, 1024)
    const void* b_qkv  = d_in[2];  // (3072,)
    const void* w_proj = d_in[3];  // (1024, 1024)
    const void* b_proj = d_in[4];  // (1024,)

    char* ws = (char*)d_ws;
    bf16*  qkv      = (bf16*)(ws);                 // 25,165,824 B  [b][n][3C]
    bf16*  Vt       = (bf16*)(ws + 25165824);      //  8,388,608 B  [b][h][d][n]
    bf16*  attn_out = (bf16*)(ws + 33554432);      //  8,388,608 B  (b,n,c)
    bf16*  xb       = (bf16*)(ws + 41943040);      //  8,388,608 B
    bf16*  wqkvb    = (bf16*)(ws + 50331648);      //  6,291,456 B
    bf16*  wprojb   = (bf16*)(ws + 56623104);      //  2,097,152 B
    float* bqf      = (float*)(ws + 58720256);     //     12,288 B
    float* bpf      = (float*)(ws + 58732544);     //      4,096 B

    // 1) fused input normalization (sniff inlined per block)
    cvt_all_kernel<<<dim3(4100), dim3(256), 0, stream>>>(
        x, w_qkv, w_proj, b_qkv, b_proj, xb, wqkvb, wprojb, bqf, bpf);

    // 2) qkv = x @ w_qkv^T + b_qkv (Q,K -> qkv; V fused-transposed to Vt)
    //    128x128 tile, 8 waves, grid 768 = 3 blocks/CU = 24 waves/CU [R2]
    gemm_bt_kernel<128, 128, 2, 4, 6, true, false>
        <<<dim3(32, 24), dim3(512), 0, stream>>>(
        xb, wqkvb, bqf, qkv, 4096, 3072, 1024, Vt, (const uint16_t*)x);

    // 3) banded attention (v6: chunk-skip, 2 blocks/CU)  [R2-proven]
    attn_kernel<<<dim3(512), dim3(256), 0, stream>>>(qkv, Vt, attn_out);

    // 4) out = attn @ w_proj^T + b_proj, output dtype per sniff
    //    128x128 tile, 8 waves, grid (32,8)=256  [R2-proven config]
    gemm_bt_kernel<128, 128, 2, 4, 6, false, true>
        <<<dim3(32, 8), dim3(512), 0, stream>>>(
        attn_out, wprojb, bpf, d_out, 4096, 1024, 1024, nullptr, (const uint16_t*)x);
}